// Round 3
// baseline (1063.606 us; speedup 1.0000x reference)
//
#include <hip/hip_runtime.h>
#include <hip/hip_bf16.h>

#define T_TOK 8192
#define HDIM  1024
#define FDIM  4096
#define NEXP  8
#define NT1   16    // HDIM/64 k-tiles (ffn1)
#define NT2   16    // 1024/64 k-tiles per K-split chunk (ffn2)

typedef __attribute__((ext_vector_type(8))) short short8;
typedef __attribute__((ext_vector_type(4))) float f32x4;
typedef unsigned short u16;
typedef unsigned int   u32;

// ---------------- ws layout (bytes) ----------------
#define XB_OFF    0ull
#define W1B_OFF   (XB_OFF   + 16777216ull)
#define W3B_OFF   (W1B_OFF  + 67108864ull)
#define W2B_OFF   (W3B_OFF  + 67108864ull)
#define HBUF_OFF  (W2B_OFF  + 67108864ull)
#define CNT_OFF   (HBUF_OFF + 134217728ull)
#define HOFF_OFF  (CNT_OFF  + 64ull)
#define TLIST_OFF (HOFF_OFF + 64ull)
#define WLIST_OFF (TLIST_OFF + 262144ull)
#define WS_NEED   (WLIST_OFF + 262144ull)

__device__ __forceinline__ u16 f2bf(float f) {
  u32 u = __float_as_uint(f);
  return (u16)((u + 0x7fffu + ((u >> 16) & 1u)) >> 16);
}

__device__ __forceinline__ void gl_lds16(const void* g, void* l) {
  __builtin_amdgcn_global_load_lds(
      (const __attribute__((address_space(1))) void*)g,
      (__attribute__((address_space(3))) void*)l, 16, 0, 0);
}

__device__ __forceinline__ void bar() {
  asm volatile("" ::: "memory");
  __builtin_amdgcn_s_barrier();
  asm volatile("" ::: "memory");
}

#define VW(N) asm volatile("s_waitcnt vmcnt(" #N ")" ::: "memory")

// ---------------- fp32 -> bf16 weight conversion ----------------
__global__ __launch_bounds__(256) void convert3_kernel(
    const float* __restrict__ s0, const float* __restrict__ s1, const float* __restrict__ s2,
    u16* __restrict__ d0, u16* __restrict__ d1, u16* __restrict__ d2) {
  const int n4 = NEXP * FDIM * HDIM / 4;        // 2^23
  const int total = 3 * n4;
  int stride = gridDim.x * blockDim.x;
  for (int i = blockIdx.x * blockDim.x + threadIdx.x; i < total; i += stride) {
    int seg = i >> 23;
    int j = i & (n4 - 1);
    const float* s = seg == 0 ? s0 : (seg == 1 ? s1 : s2);
    u16* d = seg == 0 ? d0 : (seg == 1 ? d1 : d2);
    float4 v = ((const float4*)s)[j];
    u32 lo = (u32)f2bf(v.x) | ((u32)f2bf(v.y) << 16);
    u32 hi = (u32)f2bf(v.z) | ((u32)f2bf(v.w) << 16);
    ((uint2*)d)[j] = make_uint2(lo, hi);
  }
}

// ---------------- router ----------------
__global__ __launch_bounds__(256) void router_kernel(
    const float* __restrict__ x, const float* __restrict__ gw,
    float* __restrict__ logits, u16* __restrict__ xb,
    int* __restrict__ counts, int* __restrict__ tlist, float* __restrict__ wlist) {
  const int wid = threadIdx.x >> 6, lane = threadIdx.x & 63;
  const int t = blockIdx.x * 4 + wid;
  const float* xr = x + (size_t)t * HDIM + lane * 16;
  float4 xv[4];
#pragma unroll
  for (int q = 0; q < 4; ++q) xv[q] = ((const float4*)xr)[q];

  u32 pk[8];
#pragma unroll
  for (int q = 0; q < 4; ++q) {
    pk[q * 2 + 0] = (u32)f2bf(xv[q].x) | ((u32)f2bf(xv[q].y) << 16);
    pk[q * 2 + 1] = (u32)f2bf(xv[q].z) | ((u32)f2bf(xv[q].w) << 16);
  }
  u32* xbo = (u32*)(xb + (size_t)t * HDIM + lane * 16);
  ((uint4*)xbo)[0] = make_uint4(pk[0], pk[1], pk[2], pk[3]);
  ((uint4*)xbo)[1] = make_uint4(pk[4], pk[5], pk[6], pk[7]);

  float lg[NEXP];
#pragma unroll
  for (int e = 0; e < NEXP; ++e) {
    const float4* g = (const float4*)(gw + (size_t)e * HDIM + lane * 16);
    float s = 0.f;
#pragma unroll
    for (int q = 0; q < 4; ++q) {
      float4 gv = g[q];
      s += xv[q].x * gv.x + xv[q].y * gv.y + xv[q].z * gv.z + xv[q].w * gv.w;
    }
#pragma unroll
    for (int off = 32; off > 0; off >>= 1) s += __shfl_xor(s, off, 64);
    lg[e] = s;
  }
  if (lane == 0) {
    float* lo = logits + (size_t)t * NEXP;
#pragma unroll
    for (int e = 0; e < NEXP; ++e) lo[e] = lg[e];
    float v1 = -1e30f, v2 = -1e30f; int i1 = 0, i2 = 0;
#pragma unroll
    for (int e = 0; e < NEXP; ++e) {
      float le = lg[e];
      if (le > v1)      { v2 = v1; i2 = i1; v1 = le; i1 = e; }
      else if (le > v2) { v2 = le; i2 = e; }
    }
    float t2 = __expf(v2 - v1);
    float rs = 1.f / (1.f + t2);
    int p1 = atomicAdd(&counts[i1], 1);
    tlist[i1 * T_TOK + p1] = t; wlist[i1 * T_TOK + p1] = rs;
    int p2 = atomicAdd(&counts[i2], 1);
    tlist[i2 * T_TOK + p2] = t; wlist[i2 * T_TOK + p2] = t2 * rs;
  }
}

__global__ void prefix_kernel(const int* __restrict__ counts, int* __restrict__ hoff) {
  if (threadIdx.x == 0) {
    int s = 0;
    for (int e = 0; e < NEXP; ++e) { hoff[e] = s; s += counts[e]; }
    hoff[NEXP] = s;
  }
}

// ================= FFN1: 256x128 dual-B, 8-phase counted-vmcnt =================
// LDS buf (32768 u16): A[kk][256][32] @0, B1[kk][128][32] @16384, B3 @24576.
__global__ __launch_bounds__(512, 2) void ffn1_kernel(
    const u16* __restrict__ xb, const u16* __restrict__ w1b, const u16* __restrict__ w3b,
    u16* __restrict__ hbuf, const int* __restrict__ counts, const int* __restrict__ hoff,
    const int* __restrict__ tlist) {
  const int bid = blockIdx.x;
  const int e  = bid & 7;
  const int j  = bid >> 3;
  const int ct = j >> 5;           // 0..31
  const int rt = j & 31;           // 0..31 (row tile fastest)
  const int Ne = counts[e];
  if (rt * 256 >= Ne) return;

  __shared__ u16 LDS[65536];       // 128 KB

  const int tid = threadIdx.x;
  const int wid = tid >> 6, lane = tid & 63;
  const int wr = wid >> 2, wc = wid & 3;     // 2M x 4N, wave tile 128x32
  const int lr = lane & 15, lhi = lane >> 4;
  const int chn = (lhi ^ ((lr ^ (lr >> 2)) & 3)) * 8;   // swizzled read chunk (u16)

  size_t aoff0, aoff1; int ldsA0, ldsA1;
  {
    int idx = wid * 128 + lane;            // ld=0
    int r = idx >> 2, c = idx & 3;
    int grow = rt * 256 + r;
    int gi = grow < Ne ? grow : Ne - 1;
    aoff0 = (size_t)tlist[e * T_TOK + gi] * HDIM + (size_t)((c ^ ((r ^ (r >> 2)) & 3)) * 8);
    ldsA0 = (wid * 128) * 8;
    idx = wid * 128 + 64 + lane;           // ld=1
    r = idx >> 2; c = idx & 3;
    grow = rt * 256 + r;
    gi = grow < Ne ? grow : Ne - 1;
    aoff1 = (size_t)tlist[e * T_TOK + gi] * HDIM + (size_t)((c ^ ((r ^ (r >> 2)) & 3)) * 8);
    ldsA1 = (wid * 128 + 64) * 8;
  }
  size_t boff; int ldsB;
  {
    int idx = wid * 64 + lane;
    int r = idx >> 2, c = idx & 3;
    int fr = ct * 128 + r;
    boff = ((size_t)e * FDIM + fr) * HDIM + (size_t)((c ^ ((r ^ (r >> 2)) & 3)) * 8);
    ldsB = (wid * 64) * 8;
  }

#define STG_A1(T, KK, NB) do { \
  gl_lds16(xb + aoff0 + (T) * 64 + (KK) * 32, LDS + (NB) + (KK) * 8192 + ldsA0); \
  gl_lds16(xb + aoff1 + (T) * 64 + (KK) * 32, LDS + (NB) + (KK) * 8192 + ldsA1); } while (0)
#define STG_B1(T, KK, NB) do { \
  gl_lds16(w1b + boff + (T) * 64 + (KK) * 32, LDS + (NB) + 16384 + (KK) * 4096 + ldsB); \
  gl_lds16(w3b + boff + (T) * 64 + (KK) * 32, LDS + (NB) + 24576 + (KK) * 4096 + ldsB); } while (0)
#define RD_A1(CB, KK, MH) do { _Pragma("unroll") \
  for (int mm = 0; mm < 4; ++mm) \
    af[mm] = *(const short8*)(LDS + (CB) + (KK) * 8192 + (wr * 128 + (MH) * 64 + mm * 16 + lr) * 32 + chn); } while (0)
#define RD_B1(CB, KK) do { _Pragma("unroll") \
  for (int nn = 0; nn < 2; ++nn) { \
    b1f[nn] = *(const short8*)(LDS + (CB) + 16384 + (KK) * 4096 + (wc * 32 + nn * 16 + lr) * 32 + chn); \
    b3f[nn] = *(const short8*)(LDS + (CB) + 24576 + (KK) * 4096 + (wc * 32 + nn * 16 + lr) * 32 + chn); } } while (0)
#define MM1(MH) do { _Pragma("unroll") \
  for (int mm = 0; mm < 4; ++mm) { _Pragma("unroll") \
    for (int nn = 0; nn < 2; ++nn) { \
      acc1[(MH) * 4 + mm][nn] = __builtin_amdgcn_mfma_f32_16x16x32_bf16(af[mm], b1f[nn], acc1[(MH) * 4 + mm][nn], 0, 0, 0); \
      acc3[(MH) * 4 + mm][nn] = __builtin_amdgcn_mfma_f32_16x16x32_bf16(af[mm], b3f[nn], acc3[(MH) * 4 + mm][nn], 0, 0, 0); } } } while (0)

  short8 af[4], b1f[2], b3f[2];
  f32x4 acc1[8][2] = {}, acc3[8][2] = {};

  // prologue: tile 0 -> buf 0 (order: Akk0, Bkk0, Akk1, Bkk1)
  STG_A1(0, 0, 0); STG_B1(0, 0, 0); STG_A1(0, 1, 0); STG_B1(0, 1, 0);

  for (int t = 0; t < NT1 - 1; ++t) {
    const int cb = (t & 1) << 15, nb = cb ^ 32768;
    STG_A1(t + 1, 0, nb); VW(6); bar(); RD_A1(cb, 0, 0); RD_B1(cb, 0); __builtin_amdgcn_s_setprio(1); MM1(0); __builtin_amdgcn_s_setprio(0); bar();
    STG_B1(t + 1, 0, nb); VW(6); bar(); RD_A1(cb, 0, 1);               __builtin_amdgcn_s_setprio(1); MM1(1); __builtin_amdgcn_s_setprio(0); bar();
    STG_A1(t + 1, 1, nb); VW(6); bar(); RD_A1(cb, 1, 0); RD_B1(cb, 1); __builtin_amdgcn_s_setprio(1); MM1(0); __builtin_amdgcn_s_setprio(0); bar();
    STG_B1(t + 1, 1, nb); VW(6); bar(); RD_A1(cb, 1, 1);               __builtin_amdgcn_s_setprio(1); MM1(1); __builtin_amdgcn_s_setprio(0); bar();
  }
  { // tail tile (no staging): entering, outstanding = [Bkk0, Akk1, Bkk1]
    const int cb = ((NT1 - 1) & 1) << 15;
    VW(4); bar(); RD_A1(cb, 0, 0); RD_B1(cb, 0); __builtin_amdgcn_s_setprio(1); MM1(0); __builtin_amdgcn_s_setprio(0); bar();
           bar(); RD_A1(cb, 0, 1);               __builtin_amdgcn_s_setprio(1); MM1(1); __builtin_amdgcn_s_setprio(0); bar();
    VW(0); bar(); RD_A1(cb, 1, 0); RD_B1(cb, 1); __builtin_amdgcn_s_setprio(1); MM1(0); __builtin_amdgcn_s_setprio(0); bar();
           bar(); RD_A1(cb, 1, 1);               __builtin_amdgcn_s_setprio(1); MM1(1); __builtin_amdgcn_s_setprio(0); bar();
  }

  const int hb = hoff[e];
  const int rbase = rt * 256 + wr * 128 + lhi * 4;
  const int cbase = ct * 128 + wc * 32 + lr;
#pragma unroll
  for (int m = 0; m < 8; ++m)
#pragma unroll
    for (int i = 0; i < 4; ++i) {
      int grow = rbase + m * 16 + i;
      if (grow < Ne) {
        size_t rowp = (size_t)(hb + grow) * FDIM + cbase;
#pragma unroll
        for (int n = 0; n < 2; ++n) {
          float a1 = acc1[m][n][i], a3 = acc3[m][n][i];
          hbuf[rowp + n * 16] = f2bf((a1 / (1.f + __expf(-a1))) * a3);
        }
      }
    }
#undef STG_A1
#undef STG_B1
#undef RD_A1
#undef RD_B1
#undef MM1
}

// ================= FFN2: 256x256, K-split 4, 8-phase counted-vmcnt =================
// LDS buf (32768 u16): A[kk][256][32] @0, B[kk][256][32] @16384.
__global__ __launch_bounds__(512, 2) void ffn2_kernel(
    const u16* __restrict__ hbuf, const u16* __restrict__ w2b,
    float* __restrict__ out, const int* __restrict__ counts, const int* __restrict__ hoff,
    const int* __restrict__ tlist, const float* __restrict__ wlist) {
  const int bid = blockIdx.x;
  const int e  = bid & 7;
  const int j  = bid >> 3;
  const int rt = j & 31;
  const int ks = (j >> 5) & 3;
  const int ct = j >> 7;           // 0..3
  const int Ne = counts[e];
  if (rt * 256 >= Ne) return;
  const int hb = hoff[e];
  const size_t kbase = (size_t)ks * 1024;

  __shared__ u16 LDS[65536];

  const int tid = threadIdx.x;
  const int wid = tid >> 6, lane = tid & 63;
  const int wr = wid >> 2, wc = wid & 3;     // 2M x 4N, wave tile 128x64
  const int lr = lane & 15, lhi = lane >> 4;
  const int chn = (lhi ^ ((lr ^ (lr >> 2)) & 3)) * 8;

  size_t aoff0, aoff1, boff0, boff1; int ldsA0, ldsA1, ldsB0, ldsB1;
  {
    int idx = wid * 128 + lane;
    int r = idx >> 2, c = idx & 3;
    int grow = rt * 256 + r;
    int gi = grow < Ne ? grow : Ne - 1;
    aoff0 = (size_t)(hb + gi) * FDIM + kbase + (size_t)((c ^ ((r ^ (r >> 2)) & 3)) * 8);
    boff0 = ((size_t)e * HDIM + ct * 256 + r) * FDIM + kbase + (size_t)((c ^ ((r ^ (r >> 2)) & 3)) * 8);
    ldsA0 = (wid * 128) * 8; ldsB0 = ldsA0;
    idx = wid * 128 + 64 + lane;
    r = idx >> 2; c = idx & 3;
    grow = rt * 256 + r;
    gi = grow < Ne ? grow : Ne - 1;
    aoff1 = (size_t)(hb + gi) * FDIM + kbase + (size_t)((c ^ ((r ^ (r >> 2)) & 3)) * 8);
    boff1 = ((size_t)e * HDIM + ct * 256 + r) * FDIM + kbase + (size_t)((c ^ ((r ^ (r >> 2)) & 3)) * 8);
    ldsA1 = (wid * 128 + 64) * 8; ldsB1 = ldsA1;
  }

#define STG_A2(T, KK, NB) do { \
  gl_lds16(hbuf + aoff0 + (T) * 64 + (KK) * 32, LDS + (NB) + (KK) * 8192 + ldsA0); \
  gl_lds16(hbuf + aoff1 + (T) * 64 + (KK) * 32, LDS + (NB) + (KK) * 8192 + ldsA1); } while (0)
#define STG_B2(T, KK, NB) do { \
  gl_lds16(w2b + boff0 + (T) * 64 + (KK) * 32, LDS + (NB) + 16384 + (KK) * 8192 + ldsB0); \
  gl_lds16(w2b + boff1 + (T) * 64 + (KK) * 32, LDS + (NB) + 16384 + (KK) * 8192 + ldsB1); } while (0)
#define RD_A2(CB, KK, MH) do { _Pragma("unroll") \
  for (int mm = 0; mm < 4; ++mm) \
    af[mm] = *(const short8*)(LDS + (CB) + (KK) * 8192 + (wr * 128 + (MH) * 64 + mm * 16 + lr) * 32 + chn); } while (0)
#define RD_B2(CB, KK) do { _Pragma("unroll") \
  for (int nn = 0; nn < 4; ++nn) \
    bf_[nn] = *(const short8*)(LDS + (CB) + 16384 + (KK) * 8192 + (wc * 64 + nn * 16 + lr) * 32 + chn); } while (0)
#define MM2(MH) do { _Pragma("unroll") \
  for (int mm = 0; mm < 4; ++mm) { _Pragma("unroll") \
    for (int nn = 0; nn < 4; ++nn) \
      acc[(MH) * 4 + mm][nn] = __builtin_amdgcn_mfma_f32_16x16x32_bf16(af[mm], bf_[nn], acc[(MH) * 4 + mm][nn], 0, 0, 0); } } while (0)

  short8 af[4], bf_[4];
  f32x4 acc[8][4] = {};

  STG_A2(0, 0, 0); STG_B2(0, 0, 0); STG_A2(0, 1, 0); STG_B2(0, 1, 0);

  for (int t = 0; t < NT2 - 1; ++t) {
    const int cb = (t & 1) << 15, nb = cb ^ 32768;
    STG_A2(t + 1, 0, nb); VW(6); bar(); RD_A2(cb, 0, 0); RD_B2(cb, 0); __builtin_amdgcn_s_setprio(1); MM2(0); __builtin_amdgcn_s_setprio(0); bar();
    STG_B2(t + 1, 0, nb); VW(6); bar(); RD_A2(cb, 0, 1);               __builtin_amdgcn_s_setprio(1); MM2(1); __builtin_amdgcn_s_setprio(0); bar();
    STG_A2(t + 1, 1, nb); VW(6); bar(); RD_A2(cb, 1, 0); RD_B2(cb, 1); __builtin_amdgcn_s_setprio(1); MM2(0); __builtin_amdgcn_s_setprio(0); bar();
    STG_B2(t + 1, 1, nb); VW(6); bar(); RD_A2(cb, 1, 1);               __builtin_amdgcn_s_setprio(1); MM2(1); __builtin_amdgcn_s_setprio(0); bar();
  }
  {
    const int cb = ((NT2 - 1) & 1) << 15;
    VW(4); bar(); RD_A2(cb, 0, 0); RD_B2(cb, 0); __builtin_amdgcn_s_setprio(1); MM2(0); __builtin_amdgcn_s_setprio(0); bar();
           bar(); RD_A2(cb, 0, 1);               __builtin_amdgcn_s_setprio(1); MM2(1); __builtin_amdgcn_s_setprio(0); bar();
    VW(0); bar(); RD_A2(cb, 1, 0); RD_B2(cb, 1); __builtin_amdgcn_s_setprio(1); MM2(0); __builtin_amdgcn_s_setprio(0); bar();
           bar(); RD_A2(cb, 1, 1);               __builtin_amdgcn_s_setprio(1); MM2(1); __builtin_amdgcn_s_setprio(0); bar();
  }

  const int rb = rt * 256 + wr * 128 + lhi * 4;
  const int cb2 = ct * 256 + wc * 64 + lr;
#pragma unroll
  for (int m = 0; m < 8; ++m)
#pragma unroll
    for (int i = 0; i < 4; ++i) {
      int grow = rb + m * 16 + i;
      if (grow < Ne) {
        int tok = tlist[e * T_TOK + grow];
        float wt = wlist[e * T_TOK + grow];
        float* op = out + (size_t)tok * HDIM + cb2;
#pragma unroll
        for (int n = 0; n < 4; ++n)
          atomicAdd(op + n * 16, wt * acc[m][n][i]);
      }
    }
#undef STG_A2
#undef STG_B2
#undef RD_A2
#undef RD_B2
#undef MM2
}

extern "C" void kernel_launch(void* const* d_in, const int* in_sizes, int n_in,
                              void* d_out, int out_size, void* d_ws, size_t ws_size,
                              hipStream_t stream) {
  (void)in_sizes; (void)n_in; (void)out_size;
  if (ws_size < WS_NEED) return;

  const float* x  = (const float*)d_in[0];
  const float* gw = (const float*)d_in[1];
  const float* w1 = (const float*)d_in[2];
  const float* w3 = (const float*)d_in[3];
  const float* w2 = (const float*)d_in[4];
  float* out = (float*)d_out;
  float* logits = out + (size_t)T_TOK * HDIM;

  char* ws = (char*)d_ws;
  u16* xb    = (u16*)(ws + XB_OFF);
  u16* w1b   = (u16*)(ws + W1B_OFF);
  u16* w3b   = (u16*)(ws + W3B_OFF);
  u16* w2b   = (u16*)(ws + W2B_OFF);
  u16* hbuf  = (u16*)(ws + HBUF_OFF);
  int* counts = (int*)(ws + CNT_OFF);
  int* hoffp  = (int*)(ws + HOFF_OFF);
  int* tlist  = (int*)(ws + TLIST_OFF);
  float* wlist = (float*)(ws + WLIST_OFF);

  hipMemsetAsync(d_out, 0, (size_t)T_TOK * HDIM * sizeof(float), stream);
  hipMemsetAsync(counts, 0, NEXP * sizeof(int), stream);

  convert3_kernel<<<8192, 256, 0, stream>>>(w1, w3, w2, w1b, w3b, w2b);
  router_kernel<<<T_TOK / 4, 256, 0, stream>>>(x, gw, logits, xb, counts, tlist, wlist);
  prefix_kernel<<<1, 64, 0, stream>>>(counts, hoffp);
  ffn1_kernel<<<NEXP * 32 * 32, 512, 0, stream>>>(xb, w1b, w3b, hbuf, counts, hoffp, tlist);
  ffn2_kernel<<<NEXP * 4 * 4 * 32, 512, 0, stream>>>(hbuf, w2b, out, counts, hoffp, tlist, wlist);
}

// Round 4
// 1052.367 us; speedup vs baseline: 1.0107x; 1.0107x over previous
//
#include <hip/hip_runtime.h>
#include <hip/hip_bf16.h>

#define T_TOK 8192
#define HDIM  1024
#define FDIM  4096
#define NEXP  8
#define NT1   16    // HDIM/64 k-tiles (ffn1)
#define NT2   16    // 1024/64 k-tiles per K-split chunk (ffn2)

typedef __attribute__((ext_vector_type(8))) short short8;
typedef __attribute__((ext_vector_type(4))) float f32x4;
typedef unsigned short u16;
typedef unsigned int   u32;

// ---------------- ws layout (bytes) ----------------
#define XB_OFF    0ull
#define W1B_OFF   (XB_OFF   + 16777216ull)
#define W3B_OFF   (W1B_OFF  + 67108864ull)
#define W2B_OFF   (W3B_OFF  + 67108864ull)
#define HBUF_OFF  (W2B_OFF  + 67108864ull)
#define CNT_OFF   (HBUF_OFF + 134217728ull)
#define HOFF_OFF  (CNT_OFF  + 64ull)
#define TLIST_OFF (HOFF_OFF + 64ull)
#define WLIST_OFF (TLIST_OFF + 262144ull)
#define WS_NEED   (WLIST_OFF + 262144ull)

__device__ __forceinline__ u16 f2bf(float f) {
  u32 u = __float_as_uint(f);
  return (u16)((u + 0x7fffu + ((u >> 16) & 1u)) >> 16);
}

__device__ __forceinline__ void gl_lds16(const void* g, void* l) {
  __builtin_amdgcn_global_load_lds(
      (const __attribute__((address_space(1))) void*)g,
      (__attribute__((address_space(3))) void*)l, 16, 0, 0);
}

__device__ __forceinline__ void bar() {
  asm volatile("" ::: "memory");
  __builtin_amdgcn_s_barrier();
  asm volatile("" ::: "memory");
}

#define VW(N) asm volatile("s_waitcnt vmcnt(" #N ")" ::: "memory")
#define PRIO1 __builtin_amdgcn_s_setprio(1)
#define PRIO0 __builtin_amdgcn_s_setprio(0)

// ---------------- prep: fp32->bf16 weight convert (blocks 0..8191) + router (blocks 8192..10239) ----------------
__global__ __launch_bounds__(256) void prep_kernel(
    const float* __restrict__ x, const float* __restrict__ gw,
    const float* __restrict__ s0, const float* __restrict__ s1, const float* __restrict__ s2,
    u16* __restrict__ d0, u16* __restrict__ d1, u16* __restrict__ d2,
    float* __restrict__ logits, u16* __restrict__ xb,
    int* __restrict__ counts, int* __restrict__ tlist, float* __restrict__ wlist) {
  if (blockIdx.x < 8192) {
    const int n4 = NEXP * FDIM * HDIM / 4;      // 2^23
    const int total = 3 * n4;
    const int stride = 8192 * 256;
    for (int i = blockIdx.x * 256 + threadIdx.x; i < total; i += stride) {
      int seg = i >> 23;
      int j = i & (n4 - 1);
      const float* s = seg == 0 ? s0 : (seg == 1 ? s1 : s2);
      u16* d = seg == 0 ? d0 : (seg == 1 ? d1 : d2);
      float4 v = ((const float4*)s)[j];
      u32 lo = (u32)f2bf(v.x) | ((u32)f2bf(v.y) << 16);
      u32 hi = (u32)f2bf(v.z) | ((u32)f2bf(v.w) << 16);
      ((uint2*)d)[j] = make_uint2(lo, hi);
    }
    return;
  }
  // ---- router: one wave per token ----
  const int wid = threadIdx.x >> 6, lane = threadIdx.x & 63;
  const int t = (blockIdx.x - 8192) * 4 + wid;
  const float* xr = x + (size_t)t * HDIM + lane * 16;
  float4 xv[4];
#pragma unroll
  for (int q = 0; q < 4; ++q) xv[q] = ((const float4*)xr)[q];

  u32 pk[8];
#pragma unroll
  for (int q = 0; q < 4; ++q) {
    pk[q * 2 + 0] = (u32)f2bf(xv[q].x) | ((u32)f2bf(xv[q].y) << 16);
    pk[q * 2 + 1] = (u32)f2bf(xv[q].z) | ((u32)f2bf(xv[q].w) << 16);
  }
  u32* xbo = (u32*)(xb + (size_t)t * HDIM + lane * 16);
  ((uint4*)xbo)[0] = make_uint4(pk[0], pk[1], pk[2], pk[3]);
  ((uint4*)xbo)[1] = make_uint4(pk[4], pk[5], pk[6], pk[7]);

  float lg[NEXP];
#pragma unroll
  for (int e = 0; e < NEXP; ++e) {
    const float4* g = (const float4*)(gw + (size_t)e * HDIM + lane * 16);
    float s = 0.f;
#pragma unroll
    for (int q = 0; q < 4; ++q) {
      float4 gv = g[q];
      s += xv[q].x * gv.x + xv[q].y * gv.y + xv[q].z * gv.z + xv[q].w * gv.w;
    }
#pragma unroll
    for (int off = 32; off > 0; off >>= 1) s += __shfl_xor(s, off, 64);
    lg[e] = s;
  }
  if (lane == 0) {
    float* lo = logits + (size_t)t * NEXP;
#pragma unroll
    for (int e = 0; e < NEXP; ++e) lo[e] = lg[e];
    float v1 = -1e30f, v2 = -1e30f; int i1 = 0, i2 = 0;
#pragma unroll
    for (int e = 0; e < NEXP; ++e) {
      float le = lg[e];
      if (le > v1)      { v2 = v1; i2 = i1; v1 = le; i1 = e; }
      else if (le > v2) { v2 = le; i2 = e; }
    }
    float t2 = __expf(v2 - v1);
    float rs = 1.f / (1.f + t2);
    int p1 = atomicAdd(&counts[i1], 1);
    tlist[i1 * T_TOK + p1] = t; wlist[i1 * T_TOK + p1] = rs;
    int p2 = atomicAdd(&counts[i2], 1);
    tlist[i2 * T_TOK + p2] = t; wlist[i2 * T_TOK + p2] = t2 * rs;
  }
}

__global__ void prefix_kernel(const int* __restrict__ counts, int* __restrict__ hoff) {
  if (threadIdx.x == 0) {
    int s = 0;
    for (int e = 0; e < NEXP; ++e) { hoff[e] = s; s += counts[e]; }
    hoff[NEXP] = s;
  }
}

// ================= FFN1: 256x128 dual-B, counted-vmcnt dbuf, 128B rows =================
// LDS per buf (u16): A[256 rows mh-major][64] @0, B1[128][64] @16384, B3 @24576. buf stride 32768.
// Swizzle (R1-proven, 0 conflicts): 16B chunk c stored from source chunk c^(row&7);
// read chunk (kk*4+lhi)^(lr&7).
__global__ __launch_bounds__(512, 2) void ffn1_kernel(
    const u16* __restrict__ xb, const u16* __restrict__ w1b, const u16* __restrict__ w3b,
    u16* __restrict__ hbuf, const int* __restrict__ counts, const int* __restrict__ hoff,
    const int* __restrict__ tlist) {
  const int bid = blockIdx.x;
  const int e  = bid & 7;
  const int j  = bid >> 3;
  const int ct = j >> 5;           // 0..31
  const int rt = j & 31;           // row tile fastest
  const int Ne = counts[e];
  if (rt * 256 >= Ne) return;

  __shared__ u16 LDS[65536];       // 128 KB

  const int tid = threadIdx.x;
  const int wid = tid >> 6, lane = tid & 63;
  const int wr = wid >> 2, wc = wid & 3;     // 2M x 4N, wave tile 128x32
  const int lr = lane & 15, lhi = lane >> 4;
  const int chn0 = ((lhi)     ^ (lr & 7)) * 8;   // kk=0 read chunk (u16)
  const int chn1 = ((4 + lhi) ^ (lr & 7)) * 8;   // kk=1
  const int rA = wr * 64 + lr;                   // + mh*128 + mm*16
  const int rB = wc * 32 + lr;                   // + nn*16

  // ---- staging setup (k0-invariant). idx = q*512 + tid; dest = idx*16B (HW: base+lane*16).
  size_t aoff[4];
#pragma unroll
  for (int q = 0; q < 4; ++q) {
    int idx = q * 512 + tid;
    int s = idx >> 3, c = idx & 7;
    int g = ((s >> 6) & 1) * 128 + (s >> 7) * 64 + (s & 63);   // wr*128 + mh*64 + r6
    int grow = rt * 256 + g;
    int gi = grow < Ne ? grow : Ne - 1;
    aoff[q] = (size_t)tlist[e * T_TOK + gi] * HDIM + (size_t)((c ^ (s & 7)) * 8);
  }
  size_t boff[2];
#pragma unroll
  for (int q = 0; q < 2; ++q) {
    int idx = q * 512 + tid;
    int r = idx >> 3, c = idx & 7;
    boff[q] = ((size_t)e * FDIM + ct * 128 + r) * HDIM + (size_t)((c ^ (r & 7)) * 8);
  }
  const int dA = wid * 512;        // + q*4096 (u16, wave-uniform)
  const int dB = wid * 512;

#define SG_A0(T, NB) do { gl_lds16(xb + aoff[0] + (T) * 64, LDS + (NB) + dA); \
                          gl_lds16(xb + aoff[1] + (T) * 64, LDS + (NB) + 4096 + dA); } while (0)
#define SG_A1(T, NB) do { gl_lds16(xb + aoff[2] + (T) * 64, LDS + (NB) + 8192 + dA); \
                          gl_lds16(xb + aoff[3] + (T) * 64, LDS + (NB) + 12288 + dA); } while (0)
#define SG_B1(T, NB) do { gl_lds16(w1b + boff[0] + (T) * 64, LDS + (NB) + 16384 + dB); \
                          gl_lds16(w1b + boff[1] + (T) * 64, LDS + (NB) + 20480 + dB); } while (0)
#define SG_B3(T, NB) do { gl_lds16(w3b + boff[0] + (T) * 64, LDS + (NB) + 24576 + dB); \
                          gl_lds16(w3b + boff[1] + (T) * 64, LDS + (NB) + 28672 + dB); } while (0)
#define RDA(CB, CHN, MH) do { _Pragma("unroll") \
  for (int mm = 0; mm < 4; ++mm) \
    af[mm] = *(const short8*)(LDS + (CB) + ((MH) * 128 + rA + mm * 16) * 64 + (CHN)); } while (0)
#define RDB(CB, CHN) do { _Pragma("unroll") \
  for (int nn = 0; nn < 2; ++nn) { \
    b1f[nn] = *(const short8*)(LDS + (CB) + 16384 + (rB + nn * 16) * 64 + (CHN)); \
    b3f[nn] = *(const short8*)(LDS + (CB) + 24576 + (rB + nn * 16) * 64 + (CHN)); } } while (0)
#define MM(MH) do { _Pragma("unroll") \
  for (int mm = 0; mm < 4; ++mm) { _Pragma("unroll") \
    for (int nn = 0; nn < 2; ++nn) { \
      acc1[(MH) * 4 + mm][nn] = __builtin_amdgcn_mfma_f32_16x16x32_bf16(af[mm], b1f[nn], acc1[(MH) * 4 + mm][nn], 0, 0, 0); \
      acc3[(MH) * 4 + mm][nn] = __builtin_amdgcn_mfma_f32_16x16x32_bf16(af[mm], b3f[nn], acc3[(MH) * 4 + mm][nn], 0, 0, 0); } } } while (0)

  short8 af[4], b1f[2], b3f[2];
  f32x4 acc1[8][2] = {}, acc3[8][2] = {};

  // prologue: tile 0 -> buf 0
  SG_A0(0, 0); SG_A1(0, 0); SG_B1(0, 0); SG_B3(0, 0);

  for (int t = 0; t < NT1 - 1; ++t) {
    const int cb = (t & 1) << 15, nb = cb ^ 32768;
    // P0 (kk0,mh0): stage G0(t+1); wait tile t fully resident; compute.
    SG_A0(t + 1, nb); VW(2); bar();
    RDA(cb, chn0, 0); RDB(cb, chn0); PRIO1; MM(0); PRIO0; bar();
    // P1 (kk0,mh1)
    SG_A1(t + 1, nb);
    RDA(cb, chn0, 1); PRIO1; MM(1); PRIO0; bar();
    // P2 (kk1,mh0)
    SG_B1(t + 1, nb);
    RDA(cb, chn1, 0); RDB(cb, chn1); PRIO1; MM(0); PRIO0; bar();
    // P3 (kk1,mh1)
    SG_B3(t + 1, nb);
    RDA(cb, chn1, 1); PRIO1; MM(1); PRIO0; bar();
  }
  { // tail tile
    const int cb = ((NT1 - 1) & 1) << 15;
    VW(0); bar();
    RDA(cb, chn0, 0); RDB(cb, chn0); PRIO1; MM(0); PRIO0;
    RDA(cb, chn0, 1); PRIO1; MM(1); PRIO0;
    RDA(cb, chn1, 0); RDB(cb, chn1); PRIO1; MM(0); PRIO0;
    RDA(cb, chn1, 1); PRIO1; MM(1); PRIO0;
  }

  const int hb = hoff[e];
  const int rbase = rt * 256 + wr * 128 + lhi * 4;
  const int cbase = ct * 128 + wc * 32 + lr;
#pragma unroll
  for (int m = 0; m < 8; ++m)
#pragma unroll
    for (int i = 0; i < 4; ++i) {
      int grow = rbase + m * 16 + i;
      if (grow < Ne) {
        size_t rowp = (size_t)(hb + grow) * FDIM + cbase;
#pragma unroll
        for (int n = 0; n < 2; ++n) {
          float a1 = acc1[m][n][i], a3 = acc3[m][n][i];
          hbuf[rowp + n * 16] = f2bf((a1 / (1.f + __expf(-a1))) * a3);
        }
      }
    }
#undef SG_A0
#undef SG_A1
#undef SG_B1
#undef SG_B3
#undef RDA
#undef RDB
#undef MM
}

// ================= FFN2: 256x256, K-split 4, counted-vmcnt dbuf, 128B rows =================
// LDS per buf (u16): A[256 mh-major][64] @0, B[256][64] @16384. buf stride 32768.
__global__ __launch_bounds__(512, 2) void ffn2_kernel(
    const u16* __restrict__ hbuf, const u16* __restrict__ w2b,
    float* __restrict__ out, const int* __restrict__ counts, const int* __restrict__ hoff,
    const int* __restrict__ tlist, const float* __restrict__ wlist) {
  const int bid = blockIdx.x;
  const int e  = bid & 7;
  const int j  = bid >> 3;
  const int rt = j & 31;
  const int ks = (j >> 5) & 3;
  const int ct = j >> 7;           // 0..3
  const int Ne = counts[e];
  if (rt * 256 >= Ne) return;
  const int hb = hoff[e];
  const size_t kbase = (size_t)ks * 1024;

  __shared__ u16 LDS[65536];

  const int tid = threadIdx.x;
  const int wid = tid >> 6, lane = tid & 63;
  const int wr = wid >> 2, wc = wid & 3;     // 2M x 4N, wave tile 128x64
  const int lr = lane & 15, lhi = lane >> 4;
  const int chn0 = ((lhi)     ^ (lr & 7)) * 8;
  const int chn1 = ((4 + lhi) ^ (lr & 7)) * 8;
  const int rA = wr * 64 + lr;
  const int rB = wc * 64 + lr;

  size_t aoff[4], boff[4];
#pragma unroll
  for (int q = 0; q < 4; ++q) {
    int idx = q * 512 + tid;
    int s = idx >> 3, c = idx & 7;
    int g = ((s >> 6) & 1) * 128 + (s >> 7) * 64 + (s & 63);
    int grow = rt * 256 + g;
    int gi = grow < Ne ? grow : Ne - 1;
    aoff[q] = (size_t)(hb + gi) * FDIM + kbase + (size_t)((c ^ (s & 7)) * 8);
    int r = idx >> 3;
    boff[q] = ((size_t)e * HDIM + ct * 256 + r) * FDIM + kbase + (size_t)((c ^ (r & 7)) * 8);
  }
  const int dA = wid * 512;

#define SG_A0(T, NB) do { gl_lds16(hbuf + aoff[0] + (T) * 64, LDS + (NB) + dA); \
                          gl_lds16(hbuf + aoff[1] + (T) * 64, LDS + (NB) + 4096 + dA); } while (0)
#define SG_A1(T, NB) do { gl_lds16(hbuf + aoff[2] + (T) * 64, LDS + (NB) + 8192 + dA); \
                          gl_lds16(hbuf + aoff[3] + (T) * 64, LDS + (NB) + 12288 + dA); } while (0)
#define SG_B0(T, NB) do { gl_lds16(w2b + boff[0] + (T) * 64, LDS + (NB) + 16384 + dA); \
                          gl_lds16(w2b + boff[1] + (T) * 64, LDS + (NB) + 20480 + dA); } while (0)
#define SG_B1(T, NB) do { gl_lds16(w2b + boff[2] + (T) * 64, LDS + (NB) + 24576 + dA); \
                          gl_lds16(w2b + boff[3] + (T) * 64, LDS + (NB) + 28672 + dA); } while (0)
#define RDA(CB, CHN, MH) do { _Pragma("unroll") \
  for (int mm = 0; mm < 4; ++mm) \
    af[mm] = *(const short8*)(LDS + (CB) + ((MH) * 128 + rA + mm * 16) * 64 + (CHN)); } while (0)
#define RDB(CB, CHN) do { _Pragma("unroll") \
  for (int nn = 0; nn < 4; ++nn) \
    bf_[nn] = *(const short8*)(LDS + (CB) + 16384 + (rB + nn * 16) * 64 + (CHN)); } while (0)
#define MM(MH) do { _Pragma("unroll") \
  for (int mm = 0; mm < 4; ++mm) { _Pragma("unroll") \
    for (int nn = 0; nn < 4; ++nn) \
      acc[(MH) * 4 + mm][nn] = __builtin_amdgcn_mfma_f32_16x16x32_bf16(af[mm], bf_[nn], acc[(MH) * 4 + mm][nn], 0, 0, 0); } } while (0)

  short8 af[4], bf_[4];
  f32x4 acc[8][4] = {};

  SG_A0(0, 0); SG_A1(0, 0); SG_B0(0, 0); SG_B1(0, 0);

  for (int t = 0; t < NT2 - 1; ++t) {
    const int cb = (t & 1) << 15, nb = cb ^ 32768;
    SG_A0(t + 1, nb); VW(2); bar();
    RDA(cb, chn0, 0); RDB(cb, chn0); PRIO1; MM(0); PRIO0; bar();
    SG_A1(t + 1, nb);
    RDA(cb, chn0, 1); PRIO1; MM(1); PRIO0; bar();
    SG_B0(t + 1, nb);
    RDA(cb, chn1, 0); RDB(cb, chn1); PRIO1; MM(0); PRIO0; bar();
    SG_B1(t + 1, nb);
    RDA(cb, chn1, 1); PRIO1; MM(1); PRIO0; bar();
  }
  {
    const int cb = ((NT2 - 1) & 1) << 15;
    VW(0); bar();
    RDA(cb, chn0, 0); RDB(cb, chn0); PRIO1; MM(0); PRIO0;
    RDA(cb, chn0, 1); PRIO1; MM(1); PRIO0;
    RDA(cb, chn1, 0); RDB(cb, chn1); PRIO1; MM(0); PRIO0;
    RDA(cb, chn1, 1); PRIO1; MM(1); PRIO0;
  }

  const int rb = rt * 256 + wr * 128 + lhi * 4;
  const int cb2 = ct * 256 + wc * 64 + lr;
#pragma unroll
  for (int m = 0; m < 8; ++m)
#pragma unroll
    for (int i = 0; i < 4; ++i) {
      int grow = rb + m * 16 + i;
      if (grow < Ne) {
        int tok = tlist[e * T_TOK + grow];
        float wt = wlist[e * T_TOK + grow];
        float* op = out + (size_t)tok * HDIM + cb2;
#pragma unroll
        for (int n = 0; n < 4; ++n)
          atomicAdd(op + n * 16, wt * acc[m][n][i]);
      }
    }
#undef SG_A0
#undef SG_A1
#undef SG_B0
#undef SG_B1
#undef RDA
#undef RDB
#undef MM
}

extern "C" void kernel_launch(void* const* d_in, const int* in_sizes, int n_in,
                              void* d_out, int out_size, void* d_ws, size_t ws_size,
                              hipStream_t stream) {
  (void)in_sizes; (void)n_in; (void)out_size;
  if (ws_size < WS_NEED) return;

  const float* x  = (const float*)d_in[0];
  const float* gw = (const float*)d_in[1];
  const float* w1 = (const float*)d_in[2];
  const float* w3 = (const float*)d_in[3];
  const float* w2 = (const float*)d_in[4];
  float* out = (float*)d_out;
  float* logits = out + (size_t)T_TOK * HDIM;

  char* ws = (char*)d_ws;
  u16* xb    = (u16*)(ws + XB_OFF);
  u16* w1b   = (u16*)(ws + W1B_OFF);
  u16* w3b   = (u16*)(ws + W3B_OFF);
  u16* w2b   = (u16*)(ws + W2B_OFF);
  u16* hbuf  = (u16*)(ws + HBUF_OFF);
  int* counts = (int*)(ws + CNT_OFF);
  int* hoffp  = (int*)(ws + HOFF_OFF);
  int* tlist  = (int*)(ws + TLIST_OFF);
  float* wlist = (float*)(ws + WLIST_OFF);

  hipMemsetAsync(d_out, 0, (size_t)T_TOK * HDIM * sizeof(float), stream);
  hipMemsetAsync(counts, 0, NEXP * sizeof(int), stream);

  prep_kernel<<<8192 + 2048, 256, 0, stream>>>(x, gw, w1, w3, w2, w1b, w3b, w2b,
                                               logits, xb, counts, tlist, wlist);
  prefix_kernel<<<1, 64, 0, stream>>>(counts, hoffp);
  ffn1_kernel<<<NEXP * 32 * 32, 512, 0, stream>>>(xb, w1b, w3b, hbuf, counts, hoffp, tlist);
  ffn2_kernel<<<NEXP * 4 * 4 * 32, 512, 0, stream>>>(hbuf, w2b, out, counts, hoffp, tlist, wlist);
}

// Round 5
// 1038.873 us; speedup vs baseline: 1.0238x; 1.0130x over previous
//
#include <hip/hip_runtime.h>
#include <hip/hip_bf16.h>

#define T_TOK 8192
#define HDIM  1024
#define FDIM  4096
#define NEXP  8
#define NT1   16    // HDIM/64
#define NT2   32    // 2048/64 (K-split 2)

typedef __attribute__((ext_vector_type(8))) short short8;
typedef __attribute__((ext_vector_type(4))) float f32x4;
typedef unsigned short u16;
typedef unsigned int   u32;

// ---------------- ws layout (bytes) ----------------
#define XB_OFF    0ull
#define W1B_OFF   (XB_OFF   + 16777216ull)
#define W3B_OFF   (W1B_OFF  + 67108864ull)
#define W2B_OFF   (W3B_OFF  + 67108864ull)
#define HBUF_OFF  (W2B_OFF  + 67108864ull)
#define CNT_OFF   (HBUF_OFF + 134217728ull)
#define HOFF_OFF  (CNT_OFF  + 64ull)
#define TLIST_OFF (HOFF_OFF + 64ull)
#define WLIST_OFF (TLIST_OFF + 262144ull)
#define WS_NEED   (WLIST_OFF + 262144ull)

__device__ __forceinline__ u16 f2bf(float f) {
  u32 u = __float_as_uint(f);
  return (u16)((u + 0x7fffu + ((u >> 16) & 1u)) >> 16);
}

__device__ __forceinline__ void gl_lds16(const void* g, void* l) {
  __builtin_amdgcn_global_load_lds(
      (const __attribute__((address_space(1))) void*)g,
      (__attribute__((address_space(3))) void*)l, 16, 0, 0);
}

__device__ __forceinline__ void bar() {
  asm volatile("" ::: "memory");
  __builtin_amdgcn_s_barrier();
  asm volatile("" ::: "memory");
}

#define VW(N) asm volatile("s_waitcnt vmcnt(" #N ")" ::: "memory")
#define PRIO1 __builtin_amdgcn_s_setprio(1)
#define PRIO0 __builtin_amdgcn_s_setprio(0)

// ---------------- prep: weight convert (blocks 0..8191) + router (8192..10239) ----------------
__global__ __launch_bounds__(256) void prep_kernel(
    const float* __restrict__ x, const float* __restrict__ gw,
    const float* __restrict__ s0, const float* __restrict__ s1, const float* __restrict__ s2,
    u16* __restrict__ d0, u16* __restrict__ d1, u16* __restrict__ d2,
    float* __restrict__ logits, u16* __restrict__ xb,
    int* __restrict__ counts, int* __restrict__ tlist, float* __restrict__ wlist) {
  if (blockIdx.x < 8192) {
    const int n4 = NEXP * FDIM * HDIM / 4;      // 2^23
    const int total = 3 * n4;
    const int stride = 8192 * 256;
    for (int i = blockIdx.x * 256 + threadIdx.x; i < total; i += stride) {
      int seg = i >> 23;
      int j = i & (n4 - 1);
      const float* s = seg == 0 ? s0 : (seg == 1 ? s1 : s2);
      u16* d = seg == 0 ? d0 : (seg == 1 ? d1 : d2);
      float4 v = ((const float4*)s)[j];
      u32 lo = (u32)f2bf(v.x) | ((u32)f2bf(v.y) << 16);
      u32 hi = (u32)f2bf(v.z) | ((u32)f2bf(v.w) << 16);
      ((uint2*)d)[j] = make_uint2(lo, hi);
    }
    return;
  }
  const int wid = threadIdx.x >> 6, lane = threadIdx.x & 63;
  const int t = (blockIdx.x - 8192) * 4 + wid;
  const float* xr = x + (size_t)t * HDIM + lane * 16;
  float4 xv[4];
#pragma unroll
  for (int q = 0; q < 4; ++q) xv[q] = ((const float4*)xr)[q];

  u32 pk[8];
#pragma unroll
  for (int q = 0; q < 4; ++q) {
    pk[q * 2 + 0] = (u32)f2bf(xv[q].x) | ((u32)f2bf(xv[q].y) << 16);
    pk[q * 2 + 1] = (u32)f2bf(xv[q].z) | ((u32)f2bf(xv[q].w) << 16);
  }
  u32* xbo = (u32*)(xb + (size_t)t * HDIM + lane * 16);
  ((uint4*)xbo)[0] = make_uint4(pk[0], pk[1], pk[2], pk[3]);
  ((uint4*)xbo)[1] = make_uint4(pk[4], pk[5], pk[6], pk[7]);

  float lg[NEXP];
#pragma unroll
  for (int e = 0; e < NEXP; ++e) {
    const float4* g = (const float4*)(gw + (size_t)e * HDIM + lane * 16);
    float s = 0.f;
#pragma unroll
    for (int q = 0; q < 4; ++q) {
      float4 gv = g[q];
      s += xv[q].x * gv.x + xv[q].y * gv.y + xv[q].z * gv.z + xv[q].w * gv.w;
    }
#pragma unroll
    for (int off = 32; off > 0; off >>= 1) s += __shfl_xor(s, off, 64);
    lg[e] = s;
  }
  if (lane == 0) {
    float* lo = logits + (size_t)t * NEXP;
#pragma unroll
    for (int e = 0; e < NEXP; ++e) lo[e] = lg[e];
    float v1 = -1e30f, v2 = -1e30f; int i1 = 0, i2 = 0;
#pragma unroll
    for (int e = 0; e < NEXP; ++e) {
      float le = lg[e];
      if (le > v1)      { v2 = v1; i2 = i1; v1 = le; i1 = e; }
      else if (le > v2) { v2 = le; i2 = e; }
    }
    float t2 = __expf(v2 - v1);
    float rs = 1.f / (1.f + t2);
    int p1 = atomicAdd(&counts[i1], 1);
    tlist[i1 * T_TOK + p1] = t; wlist[i1 * T_TOK + p1] = rs;
    int p2 = atomicAdd(&counts[i2], 1);
    tlist[i2 * T_TOK + p2] = t; wlist[i2 * T_TOK + p2] = t2 * rs;
  }
}

__global__ void prefix_kernel(const int* __restrict__ counts, int* __restrict__ hoff) {
  if (threadIdx.x == 0) {
    int s = 0;
    for (int e = 0; e < NEXP; ++e) { hoff[e] = s; s += counts[e]; }
    hoff[NEXP] = s;
  }
}

// ================= FFN1: 256x256 (B = [W1ct ; W3ct]), m201 8-phase =================
// LDS per buf (u16): A @0 (rows (mh*2+sub)*64+r6, 32KB), B @16384 (rows (nh*4+wc)*32+r5, 32KB).
// buf stride 32768 u16 (64 KB). Swizzle: chunk c stored from src chunk c^(ldsrow&7); read (kk*4+lhi)^(lr&7).
__global__ __launch_bounds__(512, 2) void ffn1_kernel(
    const u16* __restrict__ xb, const u16* __restrict__ w1b, const u16* __restrict__ w3b,
    u16* __restrict__ hbuf, const int* __restrict__ counts, const int* __restrict__ hoff,
    const int* __restrict__ tlist) {
  const int bid = blockIdx.x;
  const int e  = bid & 7;
  const int j  = bid >> 3;
  const int ct = (j >> 5) & 31;    // F-block of 128 output cols
  const int rt = j & 31;
  const int Ne = counts[e];
  if (rt * 256 >= Ne) return;

  __shared__ u16 LDS[65536];       // 128 KB

  const int tid = threadIdx.x;
  const int wid = tid >> 6, lane = tid & 63;
  const int wr = wid >> 2, wc = wid & 3;     // 2M x 4N, wave tile 128x64
  const int lr = lane & 15, lhi = lane >> 4;
  const int chn0 = ((lhi)     ^ (lr & 7)) * 8;
  const int chn1 = ((4 + lhi) ^ (lr & 7)) * 8;
  const int dA = wid * 512;        // wave-uniform; HW adds lane*16B

  // ---- staging addresses ----
  const int r6 = tid >> 3;                 // 0..63
  const int swz = ((tid & 7) ^ (r6 & 7)) * 8;
  size_t aoff[2][2];
#pragma unroll
  for (int mh = 0; mh < 2; ++mh)
#pragma unroll
    for (int q = 0; q < 2; ++q) {
      int grow = rt * 256 + q * 128 + mh * 64 + r6;
      int gi = grow < Ne ? grow : Ne - 1;
      aoff[mh][q] = (size_t)tlist[e * T_TOK + gi] * HDIM + swz;
    }
  const int pb = tid >> 8, r5 = r6 & 31;
  size_t boff[2][2];               // [nh][q]: q=0 -> w1b, q=1 -> w3b
#pragma unroll
  for (int nh = 0; nh < 2; ++nh)
#pragma unroll
    for (int q = 0; q < 2; ++q)
      boff[nh][q] = ((size_t)e * FDIM + ct * 128 + pb * 64 + nh * 32 + r5) * HDIM + swz;

#define SGA(MH, T, NB) do { \
  gl_lds16(xb + aoff[MH][0] + (T) * 64, LDS + (NB) + (MH) * 8192 + dA); \
  gl_lds16(xb + aoff[MH][1] + (T) * 64, LDS + (NB) + (MH) * 8192 + 4096 + dA); } while (0)
#define SGB(NH, T, NB) do { \
  gl_lds16(w1b + boff[NH][0] + (T) * 64, LDS + (NB) + 16384 + (NH) * 8192 + dA); \
  gl_lds16(w3b + boff[NH][1] + (T) * 64, LDS + (NB) + 16384 + (NH) * 8192 + 4096 + dA); } while (0)
#define PHASE(CB, MH, NH) do { \
  short8 a0[4], a1[4], b0[2], b1[2]; \
  _Pragma("unroll") for (int mm = 0; mm < 4; ++mm) { \
    int ro = (((MH) * 2 + wr) * 64 + mm * 16 + lr) * 64; \
    a0[mm] = *(const short8*)(LDS + (CB) + ro + chn0); \
    a1[mm] = *(const short8*)(LDS + (CB) + ro + chn1); } \
  _Pragma("unroll") for (int nn = 0; nn < 2; ++nn) { \
    int ro = 16384 + (((NH) * 4 + wc) * 32 + nn * 16 + lr) * 64; \
    b0[nn] = *(const short8*)(LDS + (CB) + ro + chn0); \
    b1[nn] = *(const short8*)(LDS + (CB) + ro + chn1); } \
  PRIO1; \
  _Pragma("unroll") for (int mm = 0; mm < 4; ++mm) { \
    _Pragma("unroll") for (int nn = 0; nn < 2; ++nn) { \
      acc[(MH) * 4 + mm][(NH) * 2 + nn] = __builtin_amdgcn_mfma_f32_16x16x32_bf16(a0[mm], b0[nn], acc[(MH) * 4 + mm][(NH) * 2 + nn], 0, 0, 0); \
      acc[(MH) * 4 + mm][(NH) * 2 + nn] = __builtin_amdgcn_mfma_f32_16x16x32_bf16(a1[mm], b1[nn], acc[(MH) * 4 + mm][(NH) * 2 + nn], 0, 0, 0); } } \
  PRIO0; } while (0)

  f32x4 acc[8][4] = {};

  // prologue: tile 0
  SGA(0, 0, 0); SGB(0, 0, 0); SGA(1, 0, 0); SGB(1, 0, 0);

  for (int t = 0; t < NT1 - 1; ++t) {
    const int cb = (t & 1) << 15, nb = cb ^ 32768;
    SGA(0, t + 1, nb); SGB(0, t + 1, nb); VW(8); bar(); PHASE(cb, 0, 0); bar();
    SGA(1, t + 1, nb);                    VW(8); bar(); PHASE(cb, 1, 0); bar();
    SGB(1, t + 1, nb);                    VW(8); bar(); PHASE(cb, 0, 1); bar();
                                                        PHASE(cb, 1, 1); bar();
  }
  {
    const int cb = ((NT1 - 1) & 1) << 15;
    VW(4); bar(); PHASE(cb, 0, 0); bar();
    VW(2); bar(); PHASE(cb, 1, 0); bar();
    VW(0); bar(); PHASE(cb, 0, 1); bar();
                  PHASE(cb, 1, 1); bar();
  }

  // ---- epilogue: silu(acc_w1) * acc_w3 via LDS exchange ----
  f32x4* LF = (f32x4*)LDS;
  if (wc >= 2) {
    const int region = wr * 2 + (wc - 2);
#pragma unroll
    for (int m = 0; m < 8; ++m)
#pragma unroll
      for (int n = 0; n < 4; ++n)
        LF[region * 2048 + (m * 4 + n) * 64 + lane] = acc[m][n];
  }
  bar();
  if (wc < 2) {
    const int pair = wr * 2 + wc;
    const int hb = hoff[e];
    const int rbase = rt * 256 + wr * 128 + lhi * 4;
    const int cbase = ct * 128 + wc * 64 + lr;
#pragma unroll
    for (int m = 0; m < 8; ++m) {
#pragma unroll
      for (int n = 0; n < 4; ++n) {
        f32x4 a3 = LF[pair * 2048 + (m * 4 + n) * 64 + lane];
        f32x4 a1 = acc[m][n];
#pragma unroll
        for (int i = 0; i < 4; ++i) {
          int grow = rbase + m * 16 + i;
          if (grow < Ne) {
            float v1 = a1[i];
            hbuf[(size_t)(hb + grow) * FDIM + cbase + n * 16] =
                f2bf((v1 / (1.f + __expf(-v1))) * a3[i]);
          }
        }
      }
    }
  }
#undef SGA
#undef SGB
#undef PHASE
}

// ================= FFN2: 256x256, K-split 2, m201 8-phase =================
__global__ __launch_bounds__(512, 2) void ffn2_kernel(
    const u16* __restrict__ hbuf, const u16* __restrict__ w2b,
    float* __restrict__ out, const int* __restrict__ counts, const int* __restrict__ hoff,
    const int* __restrict__ tlist, const float* __restrict__ wlist) {
  const int bid = blockIdx.x;
  const int e  = bid & 7;
  const int j  = bid >> 3;
  const int rt = j & 31;
  const int ks = (j >> 5) & 1;
  const int ct = (j >> 6) & 3;
  const int Ne = counts[e];
  if (rt * 256 >= Ne) return;
  const int hb = hoff[e];
  const size_t kbase = (size_t)ks * 2048;

  __shared__ u16 LDS[65536];

  const int tid = threadIdx.x;
  const int wid = tid >> 6, lane = tid & 63;
  const int wr = wid >> 2, wc = wid & 3;
  const int lr = lane & 15, lhi = lane >> 4;
  const int chn0 = ((lhi)     ^ (lr & 7)) * 8;
  const int chn1 = ((4 + lhi) ^ (lr & 7)) * 8;
  const int dA = wid * 512;

  const int r6 = tid >> 3;
  const int swz = ((tid & 7) ^ (r6 & 7)) * 8;
  size_t aoff[2][2];
#pragma unroll
  for (int mh = 0; mh < 2; ++mh)
#pragma unroll
    for (int q = 0; q < 2; ++q) {
      int grow = rt * 256 + q * 128 + mh * 64 + r6;
      int gi = grow < Ne ? grow : Ne - 1;
      aoff[mh][q] = (size_t)(hb + gi) * FDIM + kbase + swz;
    }
  const int pb = tid >> 8, r5 = r6 & 31;
  size_t boff[2][2];
#pragma unroll
  for (int nh = 0; nh < 2; ++nh)
#pragma unroll
    for (int q = 0; q < 2; ++q)
      boff[nh][q] = ((size_t)e * HDIM + ct * 256 + (q * 2 + pb) * 64 + nh * 32 + r5) * FDIM + kbase + swz;

#define SGA(MH, T, NB) do { \
  gl_lds16(hbuf + aoff[MH][0] + (T) * 64, LDS + (NB) + (MH) * 8192 + dA); \
  gl_lds16(hbuf + aoff[MH][1] + (T) * 64, LDS + (NB) + (MH) * 8192 + 4096 + dA); } while (0)
#define SGB(NH, T, NB) do { \
  gl_lds16(w2b + boff[NH][0] + (T) * 64, LDS + (NB) + 16384 + (NH) * 8192 + dA); \
  gl_lds16(w2b + boff[NH][1] + (T) * 64, LDS + (NB) + 16384 + (NH) * 8192 + 4096 + dA); } while (0)
#define PHASE(CB, MH, NH) do { \
  short8 a0[4], a1[4], b0[2], b1[2]; \
  _Pragma("unroll") for (int mm = 0; mm < 4; ++mm) { \
    int ro = (((MH) * 2 + wr) * 64 + mm * 16 + lr) * 64; \
    a0[mm] = *(const short8*)(LDS + (CB) + ro + chn0); \
    a1[mm] = *(const short8*)(LDS + (CB) + ro + chn1); } \
  _Pragma("unroll") for (int nn = 0; nn < 2; ++nn) { \
    int ro = 16384 + (((NH) * 4 + wc) * 32 + nn * 16 + lr) * 64; \
    b0[nn] = *(const short8*)(LDS + (CB) + ro + chn0); \
    b1[nn] = *(const short8*)(LDS + (CB) + ro + chn1); } \
  PRIO1; \
  _Pragma("unroll") for (int mm = 0; mm < 4; ++mm) { \
    _Pragma("unroll") for (int nn = 0; nn < 2; ++nn) { \
      acc[(MH) * 4 + mm][(NH) * 2 + nn] = __builtin_amdgcn_mfma_f32_16x16x32_bf16(a0[mm], b0[nn], acc[(MH) * 4 + mm][(NH) * 2 + nn], 0, 0, 0); \
      acc[(MH) * 4 + mm][(NH) * 2 + nn] = __builtin_amdgcn_mfma_f32_16x16x32_bf16(a1[mm], b1[nn], acc[(MH) * 4 + mm][(NH) * 2 + nn], 0, 0, 0); } } \
  PRIO0; } while (0)

  f32x4 acc[8][4] = {};

  SGA(0, 0, 0); SGB(0, 0, 0); SGA(1, 0, 0); SGB(1, 0, 0);

  for (int t = 0; t < NT2 - 1; ++t) {
    const int cb = (t & 1) << 15, nb = cb ^ 32768;
    SGA(0, t + 1, nb); SGB(0, t + 1, nb); VW(8); bar(); PHASE(cb, 0, 0); bar();
    SGA(1, t + 1, nb);                    VW(8); bar(); PHASE(cb, 1, 0); bar();
    SGB(1, t + 1, nb);                    VW(8); bar(); PHASE(cb, 0, 1); bar();
                                                        PHASE(cb, 1, 1); bar();
  }
  {
    const int cb = ((NT2 - 1) & 1) << 15;
    VW(4); bar(); PHASE(cb, 0, 0); bar();
    VW(2); bar(); PHASE(cb, 1, 0); bar();
    VW(0); bar(); PHASE(cb, 0, 1); bar();
                  PHASE(cb, 1, 1);
  }

  const int rb = rt * 256 + wr * 128 + lhi * 4;
  const int cb2 = ct * 256 + wc * 64 + lr;
#pragma unroll
  for (int m = 0; m < 8; ++m)
#pragma unroll
    for (int i = 0; i < 4; ++i) {
      int grow = rb + m * 16 + i;
      if (grow < Ne) {
        int tok = tlist[e * T_TOK + grow];
        float wt = wlist[e * T_TOK + grow];
        float* op = out + (size_t)tok * HDIM + cb2;
#pragma unroll
        for (int n = 0; n < 4; ++n)
          atomicAdd(op + n * 16, wt * acc[m][n][i]);
      }
    }
#undef SGA
#undef SGB
#undef PHASE
}

extern "C" void kernel_launch(void* const* d_in, const int* in_sizes, int n_in,
                              void* d_out, int out_size, void* d_ws, size_t ws_size,
                              hipStream_t stream) {
  (void)in_sizes; (void)n_in; (void)out_size;
  if (ws_size < WS_NEED) return;

  const float* x  = (const float*)d_in[0];
  const float* gw = (const float*)d_in[1];
  const float* w1 = (const float*)d_in[2];
  const float* w3 = (const float*)d_in[3];
  const float* w2 = (const float*)d_in[4];
  float* out = (float*)d_out;
  float* logits = out + (size_t)T_TOK * HDIM;

  char* ws = (char*)d_ws;
  u16* xb    = (u16*)(ws + XB_OFF);
  u16* w1b   = (u16*)(ws + W1B_OFF);
  u16* w3b   = (u16*)(ws + W3B_OFF);
  u16* w2b   = (u16*)(ws + W2B_OFF);
  u16* hbuf  = (u16*)(ws + HBUF_OFF);
  int* counts = (int*)(ws + CNT_OFF);
  int* hoffp  = (int*)(ws + HOFF_OFF);
  int* tlist  = (int*)(ws + TLIST_OFF);
  float* wlist = (float*)(ws + WLIST_OFF);

  hipMemsetAsync(d_out, 0, (size_t)T_TOK * HDIM * sizeof(float), stream);
  hipMemsetAsync(counts, 0, NEXP * sizeof(int), stream);

  prep_kernel<<<8192 + 2048, 256, 0, stream>>>(x, gw, w1, w3, w2, w1b, w3b, w2b,
                                               logits, xb, counts, tlist, wlist);
  prefix_kernel<<<1, 64, 0, stream>>>(counts, hoffp);
  ffn1_kernel<<<NEXP * 32 * 32, 512, 0, stream>>>(xb, w1b, w3b, hbuf, counts, hoffp, tlist);
  ffn2_kernel<<<NEXP * 32 * 2 * 4, 512, 0, stream>>>(hbuf, w2b, out, counts, hoffp, tlist, wlist);
}

// Round 6
// 833.221 us; speedup vs baseline: 1.2765x; 1.2468x over previous
//
#include <hip/hip_runtime.h>
#include <hip/hip_bf16.h>

#define T_TOK 8192
#define HDIM  1024
#define FDIM  4096
#define NEXP  8

typedef __attribute__((ext_vector_type(8))) short short8;
typedef __attribute__((ext_vector_type(4))) float f32x4;
typedef unsigned short u16;
typedef unsigned int   u32;

// ---------------- ws layout (bytes) ----------------
#define XB_OFF    0ull
#define W1B_OFF   (XB_OFF   + 16777216ull)
#define W3B_OFF   (W1B_OFF  + 67108864ull)
#define W2B_OFF   (W3B_OFF  + 67108864ull)
#define HBUF_OFF  (W2B_OFF  + 67108864ull)
#define CNT_OFF   (HBUF_OFF + 134217728ull)
#define HOFF_OFF  (CNT_OFF  + 64ull)
#define TLIST_OFF (HOFF_OFF + 64ull)
#define WLIST_OFF (TLIST_OFF + 262144ull)
#define WS_NEED   (WLIST_OFF + 262144ull)

__device__ __forceinline__ u16 f2bf(float f) {           // RNE fp32 -> bf16
  u32 u = __float_as_uint(f);
  return (u16)((u + 0x7fffu + ((u >> 16) & 1u)) >> 16);
}

__device__ __forceinline__ void gl_lds16(const void* g, void* l) {
  __builtin_amdgcn_global_load_lds(
      (const __attribute__((address_space(1))) void*)g,
      (__attribute__((address_space(3))) void*)l, 16, 0, 0);
}

// ---------------- prep: weight convert (blocks 0..8191, uint4 stores) + router (8192..10239) ----------------
__global__ __launch_bounds__(256) void prep_kernel(
    const float* __restrict__ x, const float* __restrict__ gw,
    const float* __restrict__ s0, const float* __restrict__ s1, const float* __restrict__ s2,
    u16* __restrict__ d0, u16* __restrict__ d1, u16* __restrict__ d2,
    float* __restrict__ logits, u16* __restrict__ xb,
    int* __restrict__ counts, int* __restrict__ tlist, float* __restrict__ wlist) {
  if (blockIdx.x < 8192) {
    const int n8 = NEXP * FDIM * HDIM / 8;      // 2^22 per tensor
    const int total = 3 * n8;
    const int stride = 8192 * 256;
    for (int i = blockIdx.x * 256 + threadIdx.x; i < total; i += stride) {
      int seg = i >> 22;
      int j = i & (n8 - 1);
      const float* s = seg == 0 ? s0 : (seg == 1 ? s1 : s2);
      u16* d = seg == 0 ? d0 : (seg == 1 ? d1 : d2);
      float4 v0 = ((const float4*)s)[j * 2];
      float4 v1 = ((const float4*)s)[j * 2 + 1];
      uint4 o;
      o.x = (u32)f2bf(v0.x) | ((u32)f2bf(v0.y) << 16);
      o.y = (u32)f2bf(v0.z) | ((u32)f2bf(v0.w) << 16);
      o.z = (u32)f2bf(v1.x) | ((u32)f2bf(v1.y) << 16);
      o.w = (u32)f2bf(v1.z) | ((u32)f2bf(v1.w) << 16);
      ((uint4*)d)[j] = o;
    }
    return;
  }
  // ---- router: one wave per token ----
  const int wid = threadIdx.x >> 6, lane = threadIdx.x & 63;
  const int t = (blockIdx.x - 8192) * 4 + wid;
  const float* xr = x + (size_t)t * HDIM + lane * 16;
  float4 xv[4];
#pragma unroll
  for (int q = 0; q < 4; ++q) xv[q] = ((const float4*)xr)[q];

  u32 pk[8];
#pragma unroll
  for (int q = 0; q < 4; ++q) {
    pk[q * 2 + 0] = (u32)f2bf(xv[q].x) | ((u32)f2bf(xv[q].y) << 16);
    pk[q * 2 + 1] = (u32)f2bf(xv[q].z) | ((u32)f2bf(xv[q].w) << 16);
  }
  u32* xbo = (u32*)(xb + (size_t)t * HDIM + lane * 16);
  ((uint4*)xbo)[0] = make_uint4(pk[0], pk[1], pk[2], pk[3]);
  ((uint4*)xbo)[1] = make_uint4(pk[4], pk[5], pk[6], pk[7]);

  float lg[NEXP];
#pragma unroll
  for (int e = 0; e < NEXP; ++e) {
    const float4* g = (const float4*)(gw + (size_t)e * HDIM + lane * 16);
    float s = 0.f;
#pragma unroll
    for (int q = 0; q < 4; ++q) {
      float4 gv = g[q];
      s += xv[q].x * gv.x + xv[q].y * gv.y + xv[q].z * gv.z + xv[q].w * gv.w;
    }
#pragma unroll
    for (int off = 32; off > 0; off >>= 1) s += __shfl_xor(s, off, 64);
    lg[e] = s;
  }
  if (lane == 0) {
    float* lo = logits + (size_t)t * NEXP;
#pragma unroll
    for (int e = 0; e < NEXP; ++e) lo[e] = lg[e];
    float v1 = -1e30f, v2 = -1e30f; int i1 = 0, i2 = 0;
#pragma unroll
    for (int e = 0; e < NEXP; ++e) {
      float le = lg[e];
      if (le > v1)      { v2 = v1; i2 = i1; v1 = le; i1 = e; }
      else if (le > v2) { v2 = le; i2 = e; }
    }
    float t2 = __expf(v2 - v1);
    float rs = 1.f / (1.f + t2);
    int p1 = atomicAdd(&counts[i1], 1);
    tlist[i1 * T_TOK + p1] = t; wlist[i1 * T_TOK + p1] = rs;
    int p2 = atomicAdd(&counts[i2], 1);
    tlist[i2 * T_TOK + p2] = t; wlist[i2 * T_TOK + p2] = t2 * rs;
  }
}

__global__ void prefix_kernel(const int* __restrict__ counts, int* __restrict__ hoff) {
  if (threadIdx.x == 0) {
    int s = 0;
    for (int e = 0; e < NEXP; ++e) { hoff[e] = s; s += counts[e]; }
    hoff[NEXP] = s;
  }
}

// ---------------- FFN1: h = silu(x@w1^T)*(x@w3^T), 128x128, 8 waves (64x32/wave) ----------------
// R1-proven 2-barrier structure + zero-conflict XOR layout; 512 threads for 16 waves/CU TLP.
__global__ __launch_bounds__(512, 2) void ffn1_kernel(
    const u16* __restrict__ xb, const u16* __restrict__ w1b, const u16* __restrict__ w3b,
    u16* __restrict__ hbuf, const int* __restrict__ counts, const int* __restrict__ hoff,
    const int* __restrict__ tlist) {
  const int bid = blockIdx.x;
  const int e  = bid & 7;          // expert == XCD (L2 locality)
  const int j  = bid >> 3;         // 0..2047
  const int ct = j >> 6;           // F col tile 0..31
  const int rt = j & 63;           // row tile fastest -> B panel L2-resident
  const int Ne = counts[e];
  if (rt * 128 >= Ne) return;

  __shared__ u16 LDS[24576];       // A @0 (16KB), B1 @8192 (16KB), B3 @16384 (16KB)

  const int tid = threadIdx.x;
  const int wid = tid >> 6, lane = tid & 63;
  const int wr = wid >> 2, wc = wid & 3;     // 2M x 4N, wave tile 64x32
  const int lr = lane & 15, lhi = lane >> 4;

  // staging: idx = q*512 + tid, row = idx>>3, chunk = idx&7; src chunk pre-swizzled (rule #21)
  size_t aoff[2], b1off[2], b3off[2];
#pragma unroll
  for (int q = 0; q < 2; ++q) {
    int idx = q * 512 + tid;
    int r = idx >> 3, c = idx & 7;
    int sw = (c ^ (r & 7)) * 8;
    int grow = rt * 128 + r;
    int gi = grow < Ne ? grow : Ne - 1;
    aoff[q]  = (size_t)tlist[e * T_TOK + gi] * HDIM + sw;
    int fr = ct * 128 + r;
    b1off[q] = ((size_t)e * FDIM + fr) * HDIM + sw;
    b3off[q] = b1off[q];
  }
  const int dW = wid * 512;        // wave-uniform LDS base (u16); HW adds lane*16B

  f32x4 acc1[4][2] = {}, acc3[4][2] = {};

  for (int k0 = 0; k0 < HDIM; k0 += 64) {
    __syncthreads();
#pragma unroll
    for (int q = 0; q < 2; ++q) {
      gl_lds16(xb  + aoff[q]  + k0, LDS + q * 4096 + dW);
      gl_lds16(w1b + b1off[q] + k0, LDS + 8192 + q * 4096 + dW);
      gl_lds16(w3b + b3off[q] + k0, LDS + 16384 + q * 4096 + dW);
    }
    __syncthreads();
#pragma unroll
    for (int kk = 0; kk < 2; ++kk) {
      const int chn = ((kk * 4 + lhi) ^ (lr & 7)) * 8;   // swizzled read chunk
      short8 af[4], b1f[2], b3f[2];
#pragma unroll
      for (int m = 0; m < 4; ++m)
        af[m] = *(const short8*)(LDS + (wr * 64 + m * 16 + lr) * 64 + chn);
#pragma unroll
      for (int n = 0; n < 2; ++n) {
        int ro = (wc * 32 + n * 16 + lr) * 64 + chn;
        b1f[n] = *(const short8*)(LDS + 8192 + ro);
        b3f[n] = *(const short8*)(LDS + 16384 + ro);
      }
#pragma unroll
      for (int m = 0; m < 4; ++m)
#pragma unroll
        for (int n = 0; n < 2; ++n) {
          acc1[m][n] = __builtin_amdgcn_mfma_f32_16x16x32_bf16(af[m], b1f[n], acc1[m][n], 0, 0, 0);
          acc3[m][n] = __builtin_amdgcn_mfma_f32_16x16x32_bf16(af[m], b3f[n], acc3[m][n], 0, 0, 0);
        }
    }
  }

  const int hb = hoff[e];
  const int rbase = rt * 128 + wr * 64 + lhi * 4;
  const int cbase = ct * 128 + wc * 32 + lr;
#pragma unroll
  for (int m = 0; m < 4; ++m)
#pragma unroll
    for (int i = 0; i < 4; ++i) {
      int grow = rbase + m * 16 + i;
      if (grow < Ne) {
        size_t rowp = (size_t)(hb + grow) * FDIM + cbase;
#pragma unroll
        for (int n = 0; n < 2; ++n) {
          float a1 = acc1[m][n][i], a3 = acc3[m][n][i];
          hbuf[rowp + n * 16] = f2bf((a1 / (1.f + __expf(-a1))) * a3);
        }
      }
    }
}

// ---------------- FFN2: out[tok] += w * (h @ w2^T) — exact R1 structure ----------------
__global__ __launch_bounds__(256, 2) void ffn2_kernel(
    const u16* __restrict__ hbuf, const u16* __restrict__ w2b,
    float* __restrict__ out, const int* __restrict__ counts, const int* __restrict__ hoff,
    const int* __restrict__ tlist, const float* __restrict__ wlist) {
  const int bid = blockIdx.x;
  const int e  = bid & 7;
  const int j  = bid >> 3;
  const int ct = j >> 6;           // H col tile 0..7
  const int rt = j & 63;
  const int Ne = counts[e];
  if (rt * 128 >= Ne) return;
  const int hb = hoff[e];

  __shared__ u16 Alds[128 * 64];
  __shared__ u16 Blds[128 * 64];

  const int tid = threadIdx.x;
  const int wid = tid >> 6, lane = tid & 63;
  const int wr = wid >> 1, wc = wid & 1;
  const int lr = lane & 15, lhi = lane >> 4;

  size_t aoff[4], boff[4]; int ldso[4];
#pragma unroll
  for (int q = 0; q < 4; ++q) {
    int i = wid * 4 + q;
    int r = i * 8 + (lane >> 3);
    int sw = ((lane & 7) ^ (r & 7)) * 8;
    int grow = rt * 128 + r;
    int gi = grow < Ne ? grow : Ne - 1;
    aoff[q] = (size_t)(hb + gi) * FDIM + sw;
    int hr = ct * 128 + r;
    boff[q] = ((size_t)e * HDIM + hr) * FDIM + sw;
    ldso[q] = i * 512;
  }

  f32x4 acc[4][4] = {};

  for (int k0 = 0; k0 < FDIM; k0 += 64) {
    __syncthreads();
#pragma unroll
    for (int q = 0; q < 4; ++q) {
      gl_lds16(hbuf + aoff[q] + k0, Alds + ldso[q]);
      gl_lds16(w2b + boff[q] + k0, Blds + ldso[q]);
    }
    __syncthreads();
#pragma unroll
    for (int kk = 0; kk < 2; ++kk) {
      const int swo = ((kk * 4 + lhi) ^ (lr & 7)) * 8;
      short8 af[4], bf_[4];
#pragma unroll
      for (int m = 0; m < 4; ++m)
        af[m] = *(const short8*)(Alds + (wr * 64 + m * 16 + lr) * 64 + swo);
#pragma unroll
      for (int n = 0; n < 4; ++n)
        bf_[n] = *(const short8*)(Blds + (wc * 64 + n * 16 + lr) * 64 + swo);
#pragma unroll
      for (int m = 0; m < 4; ++m)
#pragma unroll
        for (int n = 0; n < 4; ++n)
          acc[m][n] = __builtin_amdgcn_mfma_f32_16x16x32_bf16(af[m], bf_[n], acc[m][n], 0, 0, 0);
    }
  }

  const int rb = rt * 128 + wr * 64 + lhi * 4;
  const int cb = ct * 128 + wc * 64 + lr;
#pragma unroll
  for (int m = 0; m < 4; ++m)
#pragma unroll
    for (int i = 0; i < 4; ++i) {
      int grow = rb + m * 16 + i;
      if (grow < Ne) {
        int tok = tlist[e * T_TOK + grow];
        float wt = wlist[e * T_TOK + grow];
        float* op = out + (size_t)tok * HDIM + cb;
#pragma unroll
        for (int n = 0; n < 4; ++n)
          atomicAdd(op + n * 16, wt * acc[m][n][i]);
      }
    }
}

extern "C" void kernel_launch(void* const* d_in, const int* in_sizes, int n_in,
                              void* d_out, int out_size, void* d_ws, size_t ws_size,
                              hipStream_t stream) {
  (void)in_sizes; (void)n_in; (void)out_size;
  if (ws_size < WS_NEED) return;

  const float* x  = (const float*)d_in[0];
  const float* gw = (const float*)d_in[1];
  const float* w1 = (const float*)d_in[2];
  const float* w3 = (const float*)d_in[3];
  const float* w2 = (const float*)d_in[4];
  float* out = (float*)d_out;
  float* logits = out + (size_t)T_TOK * HDIM;

  char* ws = (char*)d_ws;
  u16* xb    = (u16*)(ws + XB_OFF);
  u16* w1b   = (u16*)(ws + W1B_OFF);
  u16* w3b   = (u16*)(ws + W3B_OFF);
  u16* w2b   = (u16*)(ws + W2B_OFF);
  u16* hbuf  = (u16*)(ws + HBUF_OFF);
  int* counts = (int*)(ws + CNT_OFF);
  int* hoffp  = (int*)(ws + HOFF_OFF);
  int* tlist  = (int*)(ws + TLIST_OFF);
  float* wlist = (float*)(ws + WLIST_OFF);

  hipMemsetAsync(d_out, 0, (size_t)T_TOK * HDIM * sizeof(float), stream);
  hipMemsetAsync(counts, 0, NEXP * sizeof(int), stream);

  prep_kernel<<<8192 + 2048, 256, 0, stream>>>(x, gw, w1, w3, w2, w1b, w3b, w2b,
                                               logits, xb, counts, tlist, wlist);
  prefix_kernel<<<1, 64, 0, stream>>>(counts, hoffp);
  ffn1_kernel<<<NEXP * 64 * 32, 512, 0, stream>>>(xb, w1b, w3b, hbuf, counts, hoffp, tlist);
  ffn2_kernel<<<NEXP * 64 * 8, 256, 0, stream>>>(hbuf, w2b, out, counts, hoffp, tlist, wlist);
}

// Round 7
// 832.737 us; speedup vs baseline: 1.2772x; 1.0006x over previous
//
#include <hip/hip_runtime.h>
#include <hip/hip_bf16.h>

#define T_TOK 8192
#define HDIM  1024
#define FDIM  4096
#define NEXP  8
#define CVT_BLKS 2048

typedef __attribute__((ext_vector_type(8))) short short8;
typedef __attribute__((ext_vector_type(4))) float f32x4;
typedef unsigned short u16;
typedef unsigned int   u32;

// ---------------- ws layout (bytes) ----------------
#define XB_OFF    0ull
#define W1B_OFF   (XB_OFF   + 16777216ull)
#define W3B_OFF   (W1B_OFF  + 67108864ull)
#define W2B_OFF   (W3B_OFF  + 67108864ull)
#define HBUF_OFF  (W2B_OFF  + 67108864ull)
#define CNT_OFF   (HBUF_OFF + 134217728ull)
#define HOFF_OFF  (CNT_OFF  + 64ull)
#define TLIST_OFF (HOFF_OFF + 64ull)
#define WLIST_OFF (TLIST_OFF + 262144ull)
#define WS_NEED   (WLIST_OFF + 262144ull)

__device__ __forceinline__ u16 f2bf(float f) {           // RNE fp32 -> bf16
  u32 u = __float_as_uint(f);
  return (u16)((u + 0x7fffu + ((u >> 16) & 1u)) >> 16);
}

__device__ __forceinline__ void gl_lds16(const void* g, void* l) {
  __builtin_amdgcn_global_load_lds(
      (const __attribute__((address_space(1))) void*)g,
      (__attribute__((address_space(3))) void*)l, 16, 0, 0);
}

// ---------------- prep: w1/w3 convert (blocks 0..8191) + router (8192..10239) ----------------
__global__ __launch_bounds__(256) void prep_kernel(
    const float* __restrict__ x, const float* __restrict__ gw,
    const float* __restrict__ s0, const float* __restrict__ s1,
    u16* __restrict__ d0, u16* __restrict__ d1,
    float* __restrict__ logits, u16* __restrict__ xb,
    int* __restrict__ counts, int* __restrict__ tlist, float* __restrict__ wlist) {
  if (blockIdx.x < 8192) {
    const int n8 = NEXP * FDIM * HDIM / 8;      // 2^22 per tensor
    const int total = 2 * n8;
    const int stride = 8192 * 256;
    for (int i = blockIdx.x * 256 + threadIdx.x; i < total; i += stride) {
      int seg = i >> 22;
      int j = i & (n8 - 1);
      const float* s = seg == 0 ? s0 : s1;
      u16* d = seg == 0 ? d0 : d1;
      float4 v0 = ((const float4*)s)[j * 2];
      float4 v1 = ((const float4*)s)[j * 2 + 1];
      uint4 o;
      o.x = (u32)f2bf(v0.x) | ((u32)f2bf(v0.y) << 16);
      o.y = (u32)f2bf(v0.z) | ((u32)f2bf(v0.w) << 16);
      o.z = (u32)f2bf(v1.x) | ((u32)f2bf(v1.y) << 16);
      o.w = (u32)f2bf(v1.z) | ((u32)f2bf(v1.w) << 16);
      ((uint4*)d)[j] = o;
    }
    return;
  }
  // ---- router: one wave per token ----
  const int wid = threadIdx.x >> 6, lane = threadIdx.x & 63;
  const int t = (blockIdx.x - 8192) * 4 + wid;
  const float* xr = x + (size_t)t * HDIM + lane * 16;
  float4 xv[4];
#pragma unroll
  for (int q = 0; q < 4; ++q) xv[q] = ((const float4*)xr)[q];

  u32 pk[8];
#pragma unroll
  for (int q = 0; q < 4; ++q) {
    pk[q * 2 + 0] = (u32)f2bf(xv[q].x) | ((u32)f2bf(xv[q].y) << 16);
    pk[q * 2 + 1] = (u32)f2bf(xv[q].z) | ((u32)f2bf(xv[q].w) << 16);
  }
  u32* xbo = (u32*)(xb + (size_t)t * HDIM + lane * 16);
  ((uint4*)xbo)[0] = make_uint4(pk[0], pk[1], pk[2], pk[3]);
  ((uint4*)xbo)[1] = make_uint4(pk[4], pk[5], pk[6], pk[7]);

  float lg[NEXP];
#pragma unroll
  for (int e = 0; e < NEXP; ++e) {
    const float4* g = (const float4*)(gw + (size_t)e * HDIM + lane * 16);
    float s = 0.f;
#pragma unroll
    for (int q = 0; q < 4; ++q) {
      float4 gv = g[q];
      s += xv[q].x * gv.x + xv[q].y * gv.y + xv[q].z * gv.z + xv[q].w * gv.w;
    }
#pragma unroll
    for (int off = 32; off > 0; off >>= 1) s += __shfl_xor(s, off, 64);
    lg[e] = s;
  }
  if (lane == 0) {
    float* lo = logits + (size_t)t * NEXP;
#pragma unroll
    for (int e = 0; e < NEXP; ++e) lo[e] = lg[e];
    float v1 = -1e30f, v2 = -1e30f; int i1 = 0, i2 = 0;
#pragma unroll
    for (int e = 0; e < NEXP; ++e) {
      float le = lg[e];
      if (le > v1)      { v2 = v1; i2 = i1; v1 = le; i1 = e; }
      else if (le > v2) { v2 = le; i2 = e; }
    }
    float t2 = __expf(v2 - v1);
    float rs = 1.f / (1.f + t2);
    int p1 = atomicAdd(&counts[i1], 1);
    tlist[i1 * T_TOK + p1] = t; wlist[i1 * T_TOK + p1] = rs;
    int p2 = atomicAdd(&counts[i2], 1);
    tlist[i2 * T_TOK + p2] = t; wlist[i2 * T_TOK + p2] = t2 * rs;
  }
}

__global__ void prefix_kernel(const int* __restrict__ counts, int* __restrict__ hoff) {
  if (threadIdx.x == 0) {
    int s = 0;
    for (int e = 0; e < NEXP; ++e) { hoff[e] = s; s += counts[e]; }
    hoff[NEXP] = s;
  }
}

// ---------------- FFN1: 128x64 tile, 256 thr, 32KB LDS (high co-residency) ----------------
// First CVT_BLKS blocks convert w2 fp32->bf16 (overlaps with GEMM compute).
__global__ __launch_bounds__(256, 4) void ffn1_kernel(
    const u16* __restrict__ xb, const u16* __restrict__ w1b, const u16* __restrict__ w3b,
    u16* __restrict__ hbuf, const int* __restrict__ counts, const int* __restrict__ hoff,
    const int* __restrict__ tlist,
    const float* __restrict__ w2src, u16* __restrict__ w2b) {
  if (blockIdx.x < CVT_BLKS) {
    const int n8 = NEXP * HDIM * FDIM / 8;      // 2^22
    const int stride = CVT_BLKS * 256;
    for (int j = blockIdx.x * 256 + threadIdx.x; j < n8; j += stride) {
      float4 v0 = ((const float4*)w2src)[j * 2];
      float4 v1 = ((const float4*)w2src)[j * 2 + 1];
      uint4 o;
      o.x = (u32)f2bf(v0.x) | ((u32)f2bf(v0.y) << 16);
      o.y = (u32)f2bf(v0.z) | ((u32)f2bf(v0.w) << 16);
      o.z = (u32)f2bf(v1.x) | ((u32)f2bf(v1.y) << 16);
      o.w = (u32)f2bf(v1.z) | ((u32)f2bf(v1.w) << 16);
      ((uint4*)w2b)[j] = o;
    }
    return;
  }
  const int bid = blockIdx.x - CVT_BLKS;
  const int e  = bid & 7;          // expert == XCD (L2 locality)
  const int j  = bid >> 3;         // 0..4095
  const int ct = j >> 6;           // F col tile 0..63 (64 wide)
  const int rt = j & 63;           // row tile fastest
  const int Ne = counts[e];
  if (rt * 128 >= Ne) return;

  __shared__ u16 LDS[16384];       // A @0 (16KB), B1 @8192 (8KB), B3 @12288 (8KB)

  const int tid = threadIdx.x;
  const int wid = tid >> 6, lane = tid & 63;
  const int wr = wid >> 1, wc = wid & 1;     // 2M x 2N, wave tile 64x32
  const int lr = lane & 15, lhi = lane >> 4;

  // staging (idx = q*256 + tid; row = idx>>3, chunk = idx&7; src pre-swizzled, rule #21)
  size_t aoff[4];
#pragma unroll
  for (int q = 0; q < 4; ++q) {
    int idx = q * 256 + tid;
    int r = idx >> 3, c = idx & 7;
    int grow = rt * 128 + r;
    int gi = grow < Ne ? grow : Ne - 1;
    aoff[q] = (size_t)tlist[e * T_TOK + gi] * HDIM + (size_t)((c ^ (r & 7)) * 8);
  }
  size_t boff[2];
#pragma unroll
  for (int q = 0; q < 2; ++q) {
    int idx = q * 256 + tid;
    int r = idx >> 3, c = idx & 7;
    boff[q] = ((size_t)e * FDIM + ct * 64 + r) * HDIM + (size_t)((c ^ (r & 7)) * 8);
  }
  const int dW = wid * 64 * 8;     // wave-uniform (u16); HW adds lane*16B

  f32x4 acc1[4][2] = {}, acc3[4][2] = {};

  for (int k0 = 0; k0 < HDIM; k0 += 64) {
    __syncthreads();
#pragma unroll
    for (int q = 0; q < 4; ++q)
      gl_lds16(xb + aoff[q] + k0, LDS + q * 2048 + dW);
#pragma unroll
    for (int q = 0; q < 2; ++q) {
      gl_lds16(w1b + boff[q] + k0, LDS + 8192 + q * 2048 + dW);
      gl_lds16(w3b + boff[q] + k0, LDS + 12288 + q * 2048 + dW);
    }
    __syncthreads();
#pragma unroll
    for (int kk = 0; kk < 2; ++kk) {
      const int chn = ((kk * 4 + lhi) ^ (lr & 7)) * 8;
      short8 af[4], b1f[2], b3f[2];
#pragma unroll
      for (int m = 0; m < 4; ++m)
        af[m] = *(const short8*)(LDS + (wr * 64 + m * 16 + lr) * 64 + chn);
#pragma unroll
      for (int n = 0; n < 2; ++n) {
        int ro = (wc * 32 + n * 16 + lr) * 64 + chn;
        b1f[n] = *(const short8*)(LDS + 8192 + ro);
        b3f[n] = *(const short8*)(LDS + 12288 + ro);
      }
#pragma unroll
      for (int m = 0; m < 4; ++m)
#pragma unroll
        for (int n = 0; n < 2; ++n) {
          acc1[m][n] = __builtin_amdgcn_mfma_f32_16x16x32_bf16(af[m], b1f[n], acc1[m][n], 0, 0, 0);
          acc3[m][n] = __builtin_amdgcn_mfma_f32_16x16x32_bf16(af[m], b3f[n], acc3[m][n], 0, 0, 0);
        }
    }
  }

  const int hb = hoff[e];
  const int rbase = rt * 128 + wr * 64 + lhi * 4;
  const int cbase = ct * 64 + wc * 32 + lr;
#pragma unroll
  for (int m = 0; m < 4; ++m)
#pragma unroll
    for (int i = 0; i < 4; ++i) {
      int grow = rbase + m * 16 + i;
      if (grow < Ne) {
        size_t rowp = (size_t)(hb + grow) * FDIM + cbase;
#pragma unroll
        for (int n = 0; n < 2; ++n) {
          float a1 = acc1[m][n][i], a3 = acc3[m][n][i];
          hbuf[rowp + n * 16] = f2bf((a1 / (1.f + __expf(-a1))) * a3);
        }
      }
    }
}

// ---------------- FFN2: 128x64 tile, 256 thr, 24KB LDS ----------------
__global__ __launch_bounds__(256, 4) void ffn2_kernel(
    const u16* __restrict__ hbuf, const u16* __restrict__ w2b,
    float* __restrict__ out, const int* __restrict__ counts, const int* __restrict__ hoff,
    const int* __restrict__ tlist, const float* __restrict__ wlist) {
  const int bid = blockIdx.x;
  const int e  = bid & 7;
  const int j  = bid >> 3;
  const int ct = j >> 6;           // H col tile 0..15 (64 wide)
  const int rt = j & 63;
  const int Ne = counts[e];
  if (rt * 128 >= Ne) return;
  const int hb = hoff[e];

  __shared__ u16 LDS[12288];       // A @0 (16KB), B @8192 (8KB)

  const int tid = threadIdx.x;
  const int wid = tid >> 6, lane = tid & 63;
  const int wr = wid >> 1, wc = wid & 1;
  const int lr = lane & 15, lhi = lane >> 4;

  size_t aoff[4];
#pragma unroll
  for (int q = 0; q < 4; ++q) {
    int idx = q * 256 + tid;
    int r = idx >> 3, c = idx & 7;
    int grow = rt * 128 + r;
    int gi = grow < Ne ? grow : Ne - 1;
    aoff[q] = (size_t)(hb + gi) * FDIM + (size_t)((c ^ (r & 7)) * 8);
  }
  size_t boff[2];
#pragma unroll
  for (int q = 0; q < 2; ++q) {
    int idx = q * 256 + tid;
    int r = idx >> 3, c = idx & 7;
    boff[q] = ((size_t)e * HDIM + ct * 64 + r) * FDIM + (size_t)((c ^ (r & 7)) * 8);
  }
  const int dW = wid * 64 * 8;

  f32x4 acc[4][2] = {};

  for (int k0 = 0; k0 < FDIM; k0 += 64) {
    __syncthreads();
#pragma unroll
    for (int q = 0; q < 4; ++q)
      gl_lds16(hbuf + aoff[q] + k0, LDS + q * 2048 + dW);
#pragma unroll
    for (int q = 0; q < 2; ++q)
      gl_lds16(w2b + boff[q] + k0, LDS + 8192 + q * 2048 + dW);
    __syncthreads();
#pragma unroll
    for (int kk = 0; kk < 2; ++kk) {
      const int chn = ((kk * 4 + lhi) ^ (lr & 7)) * 8;
      short8 af[4], bf_[2];
#pragma unroll
      for (int m = 0; m < 4; ++m)
        af[m] = *(const short8*)(LDS + (wr * 64 + m * 16 + lr) * 64 + chn);
#pragma unroll
      for (int n = 0; n < 2; ++n)
        bf_[n] = *(const short8*)(LDS + 8192 + (wc * 32 + n * 16 + lr) * 64 + chn);
#pragma unroll
      for (int m = 0; m < 4; ++m)
#pragma unroll
        for (int n = 0; n < 2; ++n)
          acc[m][n] = __builtin_amdgcn_mfma_f32_16x16x32_bf16(af[m], bf_[n], acc[m][n], 0, 0, 0);
    }
  }

  const int rb = rt * 128 + wr * 64 + lhi * 4;
  const int cb = ct * 64 + wc * 32 + lr;
#pragma unroll
  for (int m = 0; m < 4; ++m)
#pragma unroll
    for (int i = 0; i < 4; ++i) {
      int grow = rb + m * 16 + i;
      if (grow < Ne) {
        int tok = tlist[e * T_TOK + grow];
        float wt = wlist[e * T_TOK + grow];
        float* op = out + (size_t)tok * HDIM + cb;
#pragma unroll
        for (int n = 0; n < 2; ++n)
          atomicAdd(op + n * 16, wt * acc[m][n][i]);
      }
    }
}

extern "C" void kernel_launch(void* const* d_in, const int* in_sizes, int n_in,
                              void* d_out, int out_size, void* d_ws, size_t ws_size,
                              hipStream_t stream) {
  (void)in_sizes; (void)n_in; (void)out_size;
  if (ws_size < WS_NEED) return;

  const float* x  = (const float*)d_in[0];
  const float* gw = (const float*)d_in[1];
  const float* w1 = (const float*)d_in[2];
  const float* w3 = (const float*)d_in[3];
  const float* w2 = (const float*)d_in[4];
  float* out = (float*)d_out;
  float* logits = out + (size_t)T_TOK * HDIM;

  char* ws = (char*)d_ws;
  u16* xb    = (u16*)(ws + XB_OFF);
  u16* w1b   = (u16*)(ws + W1B_OFF);
  u16* w3b   = (u16*)(ws + W3B_OFF);
  u16* w2b   = (u16*)(ws + W2B_OFF);
  u16* hbuf  = (u16*)(ws + HBUF_OFF);
  int* counts = (int*)(ws + CNT_OFF);
  int* hoffp  = (int*)(ws + HOFF_OFF);
  int* tlist  = (int*)(ws + TLIST_OFF);
  float* wlist = (float*)(ws + WLIST_OFF);

  hipMemsetAsync(d_out, 0, (size_t)T_TOK * HDIM * sizeof(float), stream);
  hipMemsetAsync(counts, 0, NEXP * sizeof(int), stream);

  prep_kernel<<<8192 + 2048, 256, 0, stream>>>(x, gw, w1, w3, w1b, w3b,
                                               logits, xb, counts, tlist, wlist);
  prefix_kernel<<<1, 64, 0, stream>>>(counts, hoffp);
  ffn1_kernel<<<CVT_BLKS + NEXP * 64 * 64, 256, 0, stream>>>(
      xb, w1b, w3b, hbuf, counts, hoffp, tlist, w2, w2b);
  ffn2_kernel<<<NEXP * 64 * 16, 256, 0, stream>>>(hbuf, w2b, out, counts, hoffp, tlist, wlist);
}